// Round 1
// baseline (126.259 us; speedup 1.0000x reference)
//
#include <hip/hip_runtime.h>

// RBF-ANN fused pipeline for MI355X.
// Stages: histogram(batch) -> scan -> scatter (counting sort) -> fused per-batch kernel.

__global__ __launch_bounds__(256) void hist_k(const int* __restrict__ batch, int n, int* __restrict__ cnt) {
    for (int i = blockIdx.x * blockDim.x + threadIdx.x; i < n; i += gridDim.x * blockDim.x)
        atomicAdd(&cnt[batch[i]], 1);
}

__global__ __launch_bounds__(512) void scan_k(const int* __restrict__ cnt, int* __restrict__ offs,
                                              int* __restrict__ cursor) {
    __shared__ int s[512];
    int t = threadIdx.x;
    s[t] = cnt[t];
    __syncthreads();
    for (int o = 1; o < 512; o <<= 1) {
        int v = (t >= o) ? s[t - o] : 0;
        __syncthreads();
        s[t] += v;
        __syncthreads();
    }
    offs[t + 1] = s[t];
    if (t == 0) offs[0] = 0;
    cursor[t] = s[t] - cnt[t];   // exclusive prefix
}

__global__ __launch_bounds__(256) void scatter_k(const int* __restrict__ batch, int n,
                                                 int* __restrict__ cursor, int* __restrict__ order) {
    for (int i = blockIdx.x * blockDim.x + threadIdx.x; i < n; i += gridDim.x * blockDim.x) {
        int p = atomicAdd(&cursor[batch[i]], 1);
        order[p] = i;
    }
}

// One block per batch. 256 threads = 4 waves.
// Thread t: h = t&63 (hidden idx), q = t>>6 (wave id). Wave q owns centers [16q, 16q+16).
__global__ __launch_bounds__(256) void fused_k(
    const float* __restrict__ x, const float* __restrict__ pos,
    const int* __restrict__ order, const int* __restrict__ offs,
    const float* __restrict__ centers, const float* __restrict__ widths,
    const float* __restrict__ W1, const float* __restrict__ b1,
    const float* __restrict__ Wa, const float* __restrict__ ba,
    const float* __restrict__ W2, const float* __restrict__ b2,
    const float* __restrict__ gamma_, const float* __restrict__ beta_,
    const float* __restrict__ W3, const float* __restrict__ b3,
    float* __restrict__ out)
{
    __shared__ float W1s[128][64];                 // 32 KB, W1s[d][h]
    __shared__ float cxs[64], cys[64], czs[64], iw2[64], Was[64], b1s[64];
    __shared__ float xs[4][128];
    __shared__ float ps[4][3];
    __shared__ float part[4][4][64];               // [node][quarter][h]
    __shared__ float x1s[4][64];
    __shared__ float rbfs[4][64];
    __shared__ float feats[64][65];                // padded, feat[c][h]
    __shared__ float wred[8];
    __shared__ float attn[64], aggs[64];

    const int t = threadIdx.x;
    const int b = blockIdx.x;
    const int h = t & 63;
    const int q = t >> 6;

    for (int k = t; k < 128 * 64; k += 256) W1s[k >> 6][k & 63] = W1[k];
    if (t < 64) {
        cxs[t] = centers[3 * t]; cys[t] = centers[3 * t + 1]; czs[t] = centers[3 * t + 2];
        float w = widths[t];
        iw2[t] = 1.0f / (w * w);
        Was[t] = Wa[t];
        b1s[t] = b1[t];
    }
    float acc[16];
    #pragma unroll
    for (int k = 0; k < 16; ++k) acc[k] = 0.f;

    const int start = offs[b], end = offs[b + 1];
    __syncthreads();

    for (int base = start; base < end; base += 4) {
        const int nn = min(4, end - base);
        // stage x rows + positions for up to 4 nodes
        for (int k = t; k < nn * 128; k += 256) {
            int n = k >> 7, d = k & 127;
            xs[n][d] = x[(size_t)order[base + n] * 128 + d];
        }
        if (t < nn * 3) {
            int n = t / 3, c = t % 3;
            ps[n][c] = pos[(size_t)order[base + n] * 3 + c];
        }
        __syncthreads();
        // x1 partials: each wave does a 32-deep slice of the 128-dot
        for (int n = 0; n < nn; ++n) {
            float s = 0.f;
            #pragma unroll
            for (int d = 0; d < 32; ++d) s += xs[n][q * 32 + d] * W1s[q * 32 + d][h];
            part[n][q][h] = s;
        }
        __syncthreads();
        // reduce partials + RBF (wave q handles node q)
        if (q < nn) {
            x1s[q][h] = part[q][0][h] + part[q][1][h] + part[q][2][h] + part[q][3][h] + b1s[h];
            float dx = ps[q][0] - cxs[h], dy = ps[q][1] - cys[h], dz = ps[q][2] - czs[h];
            float dist = sqrtf(dx * dx + dy * dy + dz * dz);
            rbfs[q][h] = __expf(-dist * iw2[h]);
        }
        __syncthreads();
        // rank-1 outer-product accumulation: acc[k] = feat[q*16+k][h]
        for (int n = 0; n < nn; ++n) {
            float xv = x1s[n][h];
            #pragma unroll
            for (int k = 0; k < 16; ++k) acc[k] += rbfs[n][q * 16 + k] * xv;
        }
        __syncthreads();   // protect xs/part for next iteration
    }

    #pragma unroll
    for (int k = 0; k < 16; ++k) feats[q * 16 + k][h] = acc[k];
    __syncthreads();

    // attention scores + softmax over C=64 (wave 0)
    if (t < 64) {
        float s = 0.f;
        #pragma unroll
        for (int hh = 0; hh < 64; ++hh) s += feats[t][hh] * Was[hh];
        s += ba[0];
        float m = s;
        #pragma unroll
        for (int o = 32; o > 0; o >>= 1) m = fmaxf(m, __shfl_xor(m, o, 64));
        float e = __expf(s - m);
        float se = e;
        #pragma unroll
        for (int o = 32; o > 0; o >>= 1) se += __shfl_xor(se, o, 64);
        attn[t] = e / se;
    }
    __syncthreads();
    if (t < 64) {
        float s = 0.f;
        #pragma unroll
        for (int c = 0; c < 64; ++c) s += attn[c] * feats[c][t];
        aggs[t] = s;
    }
    __syncthreads();

    // MLP head: h = LeakyReLU(agg @ W2 + b2), 128 outputs on threads 0..127
    float hv = 0.f;
    if (t < 128) {
        float s = 0.f;
        #pragma unroll
        for (int hh = 0; hh < 64; ++hh) s += aggs[hh] * W2[hh * 128 + t];
        s += b2[t];
        hv = (s >= 0.f) ? s : 0.2f * s;
    }
    // LayerNorm over 128 (waves 0-1 hold the data; others contribute zeros)
    float r = hv;
    #pragma unroll
    for (int o = 32; o > 0; o >>= 1) r += __shfl_xor(r, o, 64);
    if ((t & 63) == 0) wred[t >> 6] = r;
    __syncthreads();
    float mu = (wred[0] + wred[1]) * (1.f / 128.f);
    float dv = (t < 128) ? (hv - mu) : 0.f;
    r = dv * dv;
    #pragma unroll
    for (int o = 32; o > 0; o >>= 1) r += __shfl_xor(r, o, 64);
    __syncthreads();
    if ((t & 63) == 0) wred[t >> 6] = r;
    __syncthreads();
    float var = (wred[0] + wred[1]) * (1.f / 128.f);
    float rstd = rsqrtf(var + 1e-5f);
    float p = 0.f;
    if (t < 128) {
        float nv = (hv - mu) * rstd * gamma_[t] + beta_[t];
        p = nv * W3[t];
    }
    r = p;
    #pragma unroll
    for (int o = 32; o > 0; o >>= 1) r += __shfl_xor(r, o, 64);
    __syncthreads();
    if ((t & 63) == 0) wred[t >> 6] = r;
    __syncthreads();
    if (t == 0) out[b] = wred[0] + wred[1] + b3[0];
}

extern "C" void kernel_launch(void* const* d_in, const int* in_sizes, int n_in,
                              void* d_out, int out_size, void* d_ws, size_t ws_size,
                              hipStream_t stream) {
    const float* x       = (const float*)d_in[0];
    const float* pos     = (const float*)d_in[1];
    const int*   batch   = (const int*)d_in[2];
    const float* centers = (const float*)d_in[3];
    const float* widths  = (const float*)d_in[4];
    const float* W1      = (const float*)d_in[5];
    const float* b1      = (const float*)d_in[6];
    const float* Wa      = (const float*)d_in[7];
    const float* ba      = (const float*)d_in[8];
    const float* W2      = (const float*)d_in[9];
    const float* b2      = (const float*)d_in[10];
    const float* gamma_  = (const float*)d_in[11];
    const float* beta_   = (const float*)d_in[12];
    const float* W3      = (const float*)d_in[13];
    const float* b3      = (const float*)d_in[14];
    float* out = (float*)d_out;

    const int N = in_sizes[1] / 3;       // pos is [N,3]
    const int B = out_size;              // 512

    int* wsI    = (int*)d_ws;
    int* cnt    = wsI;                   // 512
    int* offs   = wsI + 512;             // 513
    int* cursor = wsI + 1026;            // 512
    int* order  = wsI + 1540;            // N

    hipMemsetAsync(cnt, 0, 512 * sizeof(int), stream);
    int blocks = (N + 255) / 256;
    hist_k<<<blocks, 256, 0, stream>>>(batch, N, cnt);
    scan_k<<<1, 512, 0, stream>>>(cnt, offs, cursor);
    scatter_k<<<blocks, 256, 0, stream>>>(batch, N, cursor, order);
    fused_k<<<B, 256, 0, stream>>>(x, pos, order, offs, centers, widths,
                                   W1, b1, Wa, ba, W2, b2, gamma_, beta_, W3, b3, out);
}

// Round 2
// 118.232 us; speedup vs baseline: 1.0679x; 1.0679x over previous
//
#include <hip/hip_runtime.h>

// RBF-ANN fused pipeline for MI355X.
// hist(batch) -> scan -> scatter (counting sort) -> featacc (N-parallel, atomic feat) -> head (per-batch).

__global__ __launch_bounds__(256) void hist_k(const int* __restrict__ batch, int n, int* __restrict__ cnt) {
    for (int i = blockIdx.x * blockDim.x + threadIdx.x; i < n; i += gridDim.x * blockDim.x)
        atomicAdd(&cnt[batch[i]], 1);
}

__global__ __launch_bounds__(512) void scan_k(const int* __restrict__ cnt, int* __restrict__ offs,
                                              int* __restrict__ cursor) {
    __shared__ int s[512];
    int t = threadIdx.x;
    s[t] = cnt[t];
    __syncthreads();
    for (int o = 1; o < 512; o <<= 1) {
        int v = (t >= o) ? s[t - o] : 0;
        __syncthreads();
        s[t] += v;
        __syncthreads();
    }
    offs[t + 1] = s[t];
    if (t == 0) offs[0] = 0;
    cursor[t] = s[t] - cnt[t];   // exclusive prefix
}

__global__ __launch_bounds__(256) void scatter_k(const int* __restrict__ batch, int n,
                                                 int* __restrict__ cursor, int* __restrict__ order) {
    for (int i = blockIdx.x * blockDim.x + threadIdx.x; i < n; i += gridDim.x * blockDim.x) {
        int p = atomicAdd(&cursor[batch[i]], 1);
        order[p] = i;
    }
}

// Phase A: each block owns 64 consecutive nodes of the sorted order.
// 256 threads = 4 waves; thread t: h = t&63 (hidden/center idx), q = t>>6 (d-quarter).
// W1 quarter column in registers; xs via LDS broadcasts; acc[16] = partial feat[q*16+k][h];
// flush with atomicAdd on batch change.
__global__ __launch_bounds__(256) void featacc_k(
    const float* __restrict__ x, const float* __restrict__ pos,
    const int* __restrict__ batch, const int* __restrict__ order,
    const float* __restrict__ centers, const float* __restrict__ widths,
    const float* __restrict__ W1, const float* __restrict__ b1,
    float* __restrict__ feats_g, int N)
{
    constexpr int TILE = 64, SUB = 16;
    __shared__ float xs[SUB][128];        // 8 KB
    __shared__ float part[SUB][4][64];    // 16 KB
    __shared__ float x1s[SUB][64];        // 4 KB
    __shared__ float rbfs[SUB][64];       // 4 KB
    __shared__ float ps[SUB][3];
    __shared__ int   bids[TILE];
    __shared__ int   ords[TILE];

    const int t = threadIdx.x;
    const int h = t & 63;
    const int q = t >> 6;
    const int base = blockIdx.x * TILE;
    const int cnt = min(TILE, N - base);

    // W1 quarter into registers: w1r[d] = W1[(32q+d)*64 + h]  (coalesced over h)
    float w1r[32];
    #pragma unroll
    for (int d = 0; d < 32; ++d) w1r[d] = W1[(size_t)(32 * q + d) * 64 + h];

    const float cx = centers[3 * h], cy = centers[3 * h + 1], cz = centers[3 * h + 2];
    const float w  = widths[h];
    const float iw2v = 1.0f / (w * w);
    const float b1v  = b1[h];

    if (t < cnt) { int o = order[base + t]; ords[t] = o; bids[t] = batch[o]; }
    __syncthreads();

    float acc[16];
    #pragma unroll
    for (int k = 0; k < 16; ++k) acc[k] = 0.f;
    int cur_b = bids[0];

    for (int sb = 0; sb < cnt; sb += SUB) {
        const int nn = min(SUB, cnt - sb);
        // stage x rows (float4) + positions
        for (int k = t; k < nn * 32; k += 256) {
            int n = k >> 5, d4 = k & 31;
            ((float4*)xs[n])[d4] = ((const float4*)(x + (size_t)ords[sb + n] * 128))[d4];
        }
        if (t < nn * 3) { int n = t / 3, c = t % 3; ps[n][c] = pos[(size_t)ords[sb + n] * 3 + c]; }
        __syncthreads();

        // partial x1 over this thread's d-quarter: xs reads are wave-uniform broadcasts
        for (int n = 0; n < nn; ++n) {
            const float4* xr = (const float4*)&xs[n][32 * q];
            float s = 0.f;
            #pragma unroll
            for (int d4 = 0; d4 < 8; ++d4) {
                float4 v = xr[d4];
                s += v.x * w1r[4 * d4] + v.y * w1r[4 * d4 + 1]
                   + v.z * w1r[4 * d4 + 2] + v.w * w1r[4 * d4 + 3];
            }
            part[n][q][h] = s;
        }
        __syncthreads();

        // reduce quarters + RBF: wave q handles nodes 4q..4q+3
        #pragma unroll
        for (int j = 0; j < 4; ++j) {
            int n = q * 4 + j;
            if (n < nn) {
                x1s[n][h] = part[n][0][h] + part[n][1][h] + part[n][2][h] + part[n][3][h] + b1v;
                float dx = ps[n][0] - cx, dy = ps[n][1] - cy, dz = ps[n][2] - cz;
                rbfs[n][h] = __expf(-sqrtf(dx * dx + dy * dy + dz * dz) * iw2v);
            }
        }
        __syncthreads();

        // outer-product accumulation; flush on batch change (block-uniform)
        for (int n = 0; n < nn; ++n) {
            int bb = bids[sb + n];
            if (bb != cur_b) {
                float* fg = feats_g + ((size_t)cur_b * 64 + q * 16) * 64 + h;
                #pragma unroll
                for (int k = 0; k < 16; ++k) { atomicAdd(fg + (size_t)k * 64, acc[k]); acc[k] = 0.f; }
                cur_b = bb;
            }
            float xv = x1s[n][h];
            const float4* rr = (const float4*)&rbfs[n][16 * q];
            #pragma unroll
            for (int k4 = 0; k4 < 4; ++k4) {
                float4 rv = rr[k4];
                acc[4 * k4 + 0] += rv.x * xv;
                acc[4 * k4 + 1] += rv.y * xv;
                acc[4 * k4 + 2] += rv.z * xv;
                acc[4 * k4 + 3] += rv.w * xv;
            }
        }
        __syncthreads();   // protect xs/part before next staging
    }
    float* fg = feats_g + ((size_t)cur_b * 64 + q * 16) * 64 + h;
    #pragma unroll
    for (int k = 0; k < 16; ++k) atomicAdd(fg + (size_t)k * 64, acc[k]);
}

// Phase B: one block (128 threads) per batch: attention softmax over C=64, agg, MLP, LN, out.
__global__ __launch_bounds__(128) void head_k(
    const float* __restrict__ feats_g,
    const float* __restrict__ Wa, const float* __restrict__ ba,
    const float* __restrict__ W2, const float* __restrict__ b2,
    const float* __restrict__ gamma_, const float* __restrict__ beta_,
    const float* __restrict__ W3, const float* __restrict__ b3,
    float* __restrict__ out)
{
    __shared__ float fbs[64][65];
    __shared__ float attn_s[64];
    __shared__ float aggs[64];
    __shared__ float red[2];
    const int t = threadIdx.x;
    const int b = blockIdx.x;
    const float* fb = feats_g + (size_t)b * 4096;

    for (int k = t; k < 1024; k += 128) {
        float4 v = ((const float4*)fb)[k];
        int c = k >> 4, d4 = (k & 15) * 4;
        fbs[c][d4] = v.x; fbs[c][d4 + 1] = v.y; fbs[c][d4 + 2] = v.z; fbs[c][d4 + 3] = v.w;
    }
    __syncthreads();

    if (t < 64) {
        float s = 0.f;
        #pragma unroll
        for (int hh = 0; hh < 64; ++hh) s += fbs[t][hh] * Wa[hh];
        s += ba[0];
        float m = s;
        #pragma unroll
        for (int o = 32; o > 0; o >>= 1) m = fmaxf(m, __shfl_xor(m, o, 64));
        float e = __expf(s - m);
        float se = e;
        #pragma unroll
        for (int o = 32; o > 0; o >>= 1) se += __shfl_xor(se, o, 64);
        attn_s[t] = e / se;
    }
    __syncthreads();
    if (t < 64) {
        float s = 0.f;
        #pragma unroll
        for (int c = 0; c < 64; ++c) s += attn_s[c] * fbs[c][t];
        aggs[t] = s;
    }
    __syncthreads();

    // MLP head, d = t (128 outputs)
    float s = 0.f;
    #pragma unroll
    for (int hh = 0; hh < 64; ++hh) s += aggs[hh] * W2[hh * 128 + t];
    s += b2[t];
    float hv = (s >= 0.f) ? s : 0.2f * s;

    // LayerNorm over 128 (2 waves)
    float r = hv;
    #pragma unroll
    for (int o = 32; o > 0; o >>= 1) r += __shfl_xor(r, o, 64);
    if ((t & 63) == 0) red[t >> 6] = r;
    __syncthreads();
    float mu = (red[0] + red[1]) * (1.f / 128.f);
    float dv = hv - mu;
    r = dv * dv;
    #pragma unroll
    for (int o = 32; o > 0; o >>= 1) r += __shfl_xor(r, o, 64);
    __syncthreads();
    if ((t & 63) == 0) red[t >> 6] = r;
    __syncthreads();
    float var = (red[0] + red[1]) * (1.f / 128.f);
    float nv = dv * rsqrtf(var + 1e-5f) * gamma_[t] + beta_[t];
    r = nv * W3[t];
    #pragma unroll
    for (int o = 32; o > 0; o >>= 1) r += __shfl_xor(r, o, 64);
    __syncthreads();
    if ((t & 63) == 0) red[t >> 6] = r;
    __syncthreads();
    if (t == 0) out[b] = red[0] + red[1] + b3[0];
}

extern "C" void kernel_launch(void* const* d_in, const int* in_sizes, int n_in,
                              void* d_out, int out_size, void* d_ws, size_t ws_size,
                              hipStream_t stream) {
    const float* x       = (const float*)d_in[0];
    const float* pos     = (const float*)d_in[1];
    const int*   batch   = (const int*)d_in[2];
    const float* centers = (const float*)d_in[3];
    const float* widths  = (const float*)d_in[4];
    const float* W1      = (const float*)d_in[5];
    const float* b1      = (const float*)d_in[6];
    const float* Wa      = (const float*)d_in[7];
    const float* ba      = (const float*)d_in[8];
    const float* W2      = (const float*)d_in[9];
    const float* b2      = (const float*)d_in[10];
    const float* gamma_  = (const float*)d_in[11];
    const float* beta_   = (const float*)d_in[12];
    const float* W3      = (const float*)d_in[13];
    const float* b3      = (const float*)d_in[14];
    float* out = (float*)d_out;

    const int N = in_sizes[1] / 3;       // pos is [N,3]
    const int B = out_size;              // 512

    // ws layout (floats/ints): [cnt 512 | offs 513 | cursor 512 | pad 3 | feats 512*4096 | order N]
    int*   wsI     = (int*)d_ws;
    int*   cnt     = wsI;
    int*   offs    = wsI + 512;
    int*   cursor  = wsI + 1026;
    float* feats_g = (float*)(wsI + 1540);
    int*   order   = wsI + 1540 + 512 * 4096;

    // one memset clears cnt+offs+cursor+feats (order fully overwritten by scatter)
    hipMemsetAsync(wsI, 0, (size_t)(1540 + 512 * 4096) * sizeof(int), stream);

    int blocks = (N + 255) / 256;
    hist_k<<<blocks, 256, 0, stream>>>(batch, N, cnt);
    scan_k<<<1, 512, 0, stream>>>(cnt, offs, cursor);
    scatter_k<<<blocks, 256, 0, stream>>>(batch, N, cursor, order);
    featacc_k<<<(N + 63) / 64, 256, 0, stream>>>(x, pos, batch, order, centers, widths,
                                                 W1, b1, feats_g, N);
    head_k<<<B, 128, 0, stream>>>(feats_g, Wa, ba, W2, b2, gamma_, beta_, W3, b3, out);
}